// Round 14
// baseline (392.127 us; speedup 1.0000x reference)
//
#include <hip/hip_runtime.h>

// Fused 4-layer RNN (LSTM,LSTM,GRU,GRU, H=64) + FC head. B=2048, T=512.
// ELASTIC layer pipeline with LDS counter sync (atomicAdd + s_sleep spin):
// 256 blocks x 1024 threads (16 waves). Layer L owns waves [4L,4L+4);
// each wave owns a 16-dim h-chunk. 8 batch rows/block at A-rows
// {0,1,4,5,8,9,12,13} -> each lane owns rows m={0,1}. 4-deep LDS rings;
// monotonic counters cnt[4] gate consumers + back-pressure. Tick reorder
// (R13): upstream spin + x-part MFMAs before own-group spin. R14: the
// m-pair elementwise is ext_vector(2) float -> v_pk_{add,mul,fma}_f32
// (packed fp32, ~halves non-trans elementwise ops); v_cvt_pk_bf16_f32
// for the h-pair; xs transposed [t][row] -> one ds_read_b64 for x-pair.
// Bias folded into MFMA C; weights pre-scaled by -log2e / -2log2e.

#define TT 512
#define SR 72            // state row stride (shorts)
#define SLOT (16 * SR)   // one ring slot (shorts)
#define LOG2E 1.44269504f

typedef __attribute__((ext_vector_type(8))) short bfrag;  // 8 bf16
typedef __attribute__((ext_vector_type(4))) float facc;   // 4 f32
typedef __attribute__((ext_vector_type(2))) float f32x2;  // pk-f32 pair

#define MFMA(a,b,c) __builtin_amdgcn_mfma_f32_16x16x32_bf16((a),(b),(c),0,0,0)

__device__ __forceinline__ short f2bf(float f){
  union { float f; unsigned u; } v; v.f = f;
  return (short)((v.u + 0x7fffu + ((v.u >> 16) & 1u)) >> 16);  // RNE
}
__device__ __forceinline__ f32x2 mk2(float a, float b){
  f32x2 r; r.x = a; r.y = b; return r;
}
// u pre-scaled by -log2e: sigma(x) = 1/(1+2^u), elementwise on pair
__device__ __forceinline__ f32x2 sigmP2(f32x2 u){
  f32x2 e; e.x = __builtin_amdgcn_exp2f(u.x); e.y = __builtin_amdgcn_exp2f(u.y);
  const f32x2 d = e + 1.0f;                 // v_pk_add_f32
  f32x2 r; r.x = __builtin_amdgcn_rcpf(d.x); r.y = __builtin_amdgcn_rcpf(d.y);
  return r;
}
// u pre-scaled by -2*log2e: tanh(x) = 2/(1+2^u) - 1
__device__ __forceinline__ f32x2 tanhP2(f32x2 u){
  f32x2 e; e.x = __builtin_amdgcn_exp2f(u.x); e.y = __builtin_amdgcn_exp2f(u.y);
  const f32x2 d = e + 1.0f;
  f32x2 r; r.x = __builtin_amdgcn_rcpf(d.x); r.y = __builtin_amdgcn_rcpf(d.y);
  return 2.0f * r - 1.0f;                   // v_pk_fma_f32
}
__device__ __forceinline__ void spin_ge(volatile int* p, int tgt){
  if (*p >= tgt) return;
  do { __builtin_amdgcn_s_sleep(1); } while (*p < tgt);
}
__device__ __forceinline__ facc bcast4(float v){
  facc b; b[0] = v; b[1] = v; b[2] = v; b[3] = v; return b;
}
// pack two f32 -> two bf16 (RNE) in one instruction
__device__ __forceinline__ unsigned pk_bf16(float lo, float hi){
  unsigned r;
  asm("v_cvt_pk_bf16_f32 %0, %1, %2" : "=v"(r) : "v"(lo), "v"(hi));
  return r;
}

__global__ __launch_bounds__(1024) void rnn_fused(
    const float* __restrict__ x,
    const float* __restrict__ lw_ih0, const float* __restrict__ lw_hh0,
    const float* __restrict__ lb_ih0, const float* __restrict__ lb_hh0,
    const float* __restrict__ lw_ih1, const float* __restrict__ lw_hh1,
    const float* __restrict__ lb_ih1, const float* __restrict__ lb_hh1,
    const float* __restrict__ gw_ih0, const float* __restrict__ gw_hh0,
    const float* __restrict__ gb_ih0, const float* __restrict__ gb_hh0,
    const float* __restrict__ gw_ih1, const float* __restrict__ gw_hh1,
    const float* __restrict__ gb_ih1, const float* __restrict__ gb_hh1,
    const float* __restrict__ fc_w, const float* __restrict__ fc_b,
    float* __restrict__ out)
{
  __shared__ __align__(16) short S0[4 * SLOT];  // h0 ring
  __shared__ __align__(16) short S1[4 * SLOT];  // h1 ring
  __shared__ __align__(16) short S2[4 * SLOT];  // h2 ring
  __shared__ __align__(16) short S3[4 * SLOT];  // h3 ring
  __shared__ float xs[TT][8];                   // x transposed: [t][row]
  __shared__ float hfin[8][68];
  __shared__ int cnt[4];

  const int tid = threadIdx.x;
  const int w     = tid >> 6;      // wave 0..15
  const int layer = w >> 2;        // 0..3
  const int lo4   = w & 3;         // h-chunk [lo4*16, lo4*16+16)
  const int l   = tid & 63;
  const int lq  = l >> 4;          // lane owns batch rows 2lq, 2lq+1
  const int lc  = l & 15;
  const int kb  = lq * 8;
  const int rb0 = blockIdx.x * 8;
  const int wrbase = (4 * lq) * SR + lo4 * 16 + lc;   // + m*SR
  volatile int* vc = cnt;

  const float SS  = -LOG2E;          // sigmoid-gate scale
  const float ST2 = -2.0f * LOG2E;   // tanh-gate scale

  // preload x transposed: xs[t][row], 4096 floats, 4/thread
  {
    const int idx = tid * 4;
    const int row = idx >> 9, t0 = idx & 511;
    const float4 v = *(const float4*)(x + (rb0 + row) * TT + t0);
    xs[t0][row] = v.x; xs[t0 + 1][row] = v.y;
    xs[t0 + 2][row] = v.z; xs[t0 + 3][row] = v.w;
  }
  for (int i = tid; i < 4 * SLOT; i += 1024) {
    S0[i] = 0; S1[i] = 0; S2[i] = 0; S3[i] = 0;
  }
  if (tid < 4) cnt[tid] = 0;
  __syncthreads();

  if (layer == 0) {
    // ============ LSTM0: K=64 (h-part; x is scalar FMA) ============
    bfrag wf[4][2];
    float wxs[4];
    facc b4[4];
    #pragma unroll
    for (int G = 0; G < 4; ++G) {
      const float sc = (G == 2) ? ST2 : SS;
      const int col = G * 64 + lo4 * 16 + lc;
      #pragma unroll
      for (int kt = 0; kt < 2; ++kt) {
        bfrag f;
        #pragma unroll
        for (int j = 0; j < 8; ++j)
          f[j] = f2bf(sc * lw_hh0[col * 64 + kt * 32 + kb + j]);
        wf[G][kt] = f;
      }
      wxs[G] = sc * lw_ih0[col];
      b4[G]  = bcast4(sc * (lb_ih0[col] + lb_hh0[col]));
    }
    f32x2 c0 = mk2(0.f, 0.f);
    #pragma unroll 2
    for (int t = 0; t < TT; ++t) {
      if (t >= 4) spin_ge(vc + 1, 4 * (t - 3));   // LSTM1 freed slot t&3
      if (t >= 1) spin_ge(vc + 0, 4 * t);         // own group done t-1
      __threadfence_block();
      const short* s = S0 + ((t - 1) & 3) * SLOT;
      const bfrag a0 = *(const bfrag*)(s + lc * SR + kb);
      const bfrag a1 = *(const bfrag*)(s + lc * SR + 32 + kb);
      facc acc[4];
      #pragma unroll
      for (int G = 0; G < 4; ++G) {
        facc z = MFMA(a0, wf[G][0], b4[G]);
        z = MFMA(a1, wf[G][1], z);
        acc[G] = z;
      }
      const f32x2 xv2 = *(const f32x2*)&xs[t][2 * lq];   // one b64 read
      const f32x2 i_ = sigmP2(mk2(acc[0][0], acc[0][1]) + xv2 * wxs[0]);
      const f32x2 f_ = sigmP2(mk2(acc[1][0], acc[1][1]) + xv2 * wxs[1]);
      const f32x2 g_ = tanhP2(mk2(acc[2][0], acc[2][1]) + xv2 * wxs[2]);
      const f32x2 o_ = sigmP2(mk2(acc[3][0], acc[3][1]) + xv2 * wxs[3]);
      c0 = f_ * c0 + i_ * g_;
      const f32x2 hh = o_ * tanhP2(c0 * ST2);
      const unsigned pk = pk_bf16(hh.x, hh.y);
      short* d = S0 + (t & 3) * SLOT;
      d[wrbase]      = (short)pk;
      d[wrbase + SR] = (short)(pk >> 16);
      __threadfence_block();
      if (l == 0) atomicAdd(&cnt[0], 1);
    }
  } else if (layer == 1) {
    // ============ LSTM1: K=128 ([h0_t | h1_{t-1}]) ============
    bfrag wxf[4][2], whf[4][2];
    facc b4[4];
    #pragma unroll
    for (int G = 0; G < 4; ++G) {
      const float sc = (G == 2) ? ST2 : SS;
      const int col = G * 64 + lo4 * 16 + lc;
      #pragma unroll
      for (int kt = 0; kt < 2; ++kt) {
        bfrag f0, f1;
        #pragma unroll
        for (int j = 0; j < 8; ++j) {
          const int o = col * 64 + kt * 32 + kb + j;
          f0[j] = f2bf(sc * lw_ih1[o]);
          f1[j] = f2bf(sc * lw_hh1[o]);
        }
        wxf[G][kt] = f0; whf[G][kt] = f1;
      }
      b4[G] = bcast4(sc * (lb_ih1[col] + lb_hh1[col]));
    }
    f32x2 c1 = mk2(0.f, 0.f);
    #pragma unroll 2
    for (int t = 0; t < TT; ++t) {
      spin_ge(vc + 0, 4 * (t + 1));               // h0[t] ready (early)
      __threadfence_block();
      const short* sx = S0 + (t & 3) * SLOT;
      const bfrag ax0 = *(const bfrag*)(sx + lc * SR + kb);
      const bfrag ax1 = *(const bfrag*)(sx + lc * SR + 32 + kb);
      facc acc[4];
      #pragma unroll
      for (int G = 0; G < 4; ++G) {               // x-part off critical path
        facc z = MFMA(ax0, wxf[G][0], b4[G]);
        z = MFMA(ax1, wxf[G][1], z);
        acc[G] = z;
      }
      if (t >= 4) spin_ge(vc + 2, 4 * (t - 3));   // GRU0 freed slot
      if (t >= 1) spin_ge(vc + 1, 4 * t);         // own group done t-1
      __threadfence_block();
      const short* sh = S1 + ((t - 1) & 3) * SLOT;
      const bfrag ah0 = *(const bfrag*)(sh + lc * SR + kb);
      const bfrag ah1 = *(const bfrag*)(sh + lc * SR + 32 + kb);
      #pragma unroll
      for (int G = 0; G < 4; ++G) {
        acc[G] = MFMA(ah0, whf[G][0], acc[G]);
        acc[G] = MFMA(ah1, whf[G][1], acc[G]);
      }
      const f32x2 i_ = sigmP2(mk2(acc[0][0], acc[0][1]));
      const f32x2 f_ = sigmP2(mk2(acc[1][0], acc[1][1]));
      const f32x2 g_ = tanhP2(mk2(acc[2][0], acc[2][1]));
      const f32x2 o_ = sigmP2(mk2(acc[3][0], acc[3][1]));
      c1 = f_ * c1 + i_ * g_;
      const f32x2 hh = o_ * tanhP2(c1 * ST2);
      const unsigned pk = pk_bf16(hh.x, hh.y);
      short* d = S1 + (t & 3) * SLOT;
      d[wrbase]      = (short)pk;
      d[wrbase + SR] = (short)(pk >> 16);
      __threadfence_block();
      if (l == 0) atomicAdd(&cnt[1], 1);
    }
  } else if (layer == 2) {
    // ============ GRU0: x-part = h1_t, h-part = h2_{t-1} ============
    bfrag gxf[3][2], ghf[3][2];
    facc brz4[2], bnx4, bnh4;
    #pragma unroll
    for (int G = 0; G < 3; ++G) {
      const float sc = (G == 2) ? ST2 : SS;
      const int col = G * 64 + lo4 * 16 + lc;
      #pragma unroll
      for (int kt = 0; kt < 2; ++kt) {
        bfrag f0, f1;
        #pragma unroll
        for (int j = 0; j < 8; ++j) {
          const int o = col * 64 + kt * 32 + kb + j;
          f0[j] = f2bf(sc * gw_ih0[o]);
          f1[j] = f2bf(sc * gw_hh0[o]);
        }
        gxf[G][kt] = f0; ghf[G][kt] = f1;
      }
      if (G < 2) brz4[G] = bcast4(sc * (gb_ih0[col] + gb_hh0[col]));
      else { bnx4 = bcast4(sc * gb_ih0[col]); bnh4 = bcast4(sc * gb_hh0[col]); }
    }
    f32x2 h2 = mk2(0.f, 0.f);
    #pragma unroll 2
    for (int t = 0; t < TT; ++t) {
      spin_ge(vc + 1, 4 * (t + 1));               // h1[t] ready (early)
      __threadfence_block();
      const short* sx = S1 + (t & 3) * SLOT;
      const bfrag ax0 = *(const bfrag*)(sx + lc * SR + kb);
      const bfrag ax1 = *(const bfrag*)(sx + lc * SR + 32 + kb);
      facc rz[2], axn;
      #pragma unroll
      for (int G = 0; G < 2; ++G) {               // x-part off critical path
        facc z = MFMA(ax0, gxf[G][0], brz4[G]);
        z = MFMA(ax1, gxf[G][1], z);
        rz[G] = z;
      }
      axn = MFMA(ax0, gxf[2][0], bnx4);
      axn = MFMA(ax1, gxf[2][1], axn);
      if (t >= 4) spin_ge(vc + 3, 4 * (t - 3));   // GRU1 freed slot
      if (t >= 1) spin_ge(vc + 2, 4 * t);         // own group done t-1
      __threadfence_block();
      const short* sh = S2 + ((t - 1) & 3) * SLOT;
      const bfrag ah0 = *(const bfrag*)(sh + lc * SR + kb);
      const bfrag ah1 = *(const bfrag*)(sh + lc * SR + 32 + kb);
      facc ahn = MFMA(ah0, ghf[2][0], bnh4);
      ahn = MFMA(ah1, ghf[2][1], ahn);
      #pragma unroll
      for (int G = 0; G < 2; ++G) {
        rz[G] = MFMA(ah0, ghf[G][0], rz[G]);
        rz[G] = MFMA(ah1, ghf[G][1], rz[G]);
      }
      const f32x2 r_ = sigmP2(mk2(rz[0][0], rz[0][1]));
      const f32x2 z_ = sigmP2(mk2(rz[1][0], rz[1][1]));
      const f32x2 n_ = tanhP2(mk2(axn[0], axn[1]) + r_ * mk2(ahn[0], ahn[1]));
      h2 = n_ + z_ * (h2 - n_);
      const unsigned pk = pk_bf16(h2.x, h2.y);
      short* d = S2 + (t & 3) * SLOT;
      d[wrbase]      = (short)pk;
      d[wrbase + SR] = (short)(pk >> 16);
      __threadfence_block();
      if (l == 0) atomicAdd(&cnt[2], 1);
    }
  } else {
    // ============ GRU1: x-part = h2_t, h-part = h3_{t-1} ============
    bfrag gxf[3][2], ghf[3][2];
    facc brz4[2], bnx4, bnh4;
    #pragma unroll
    for (int G = 0; G < 3; ++G) {
      const float sc = (G == 2) ? ST2 : SS;
      const int col = G * 64 + lo4 * 16 + lc;
      #pragma unroll
      for (int kt = 0; kt < 2; ++kt) {
        bfrag f0, f1;
        #pragma unroll
        for (int j = 0; j < 8; ++j) {
          const int o = col * 64 + kt * 32 + kb + j;
          f0[j] = f2bf(sc * gw_ih1[o]);
          f1[j] = f2bf(sc * gw_hh1[o]);
        }
        gxf[G][kt] = f0; ghf[G][kt] = f1;
      }
      if (G < 2) brz4[G] = bcast4(sc * (gb_ih1[col] + gb_hh1[col]));
      else { bnx4 = bcast4(sc * gb_ih1[col]); bnh4 = bcast4(sc * gb_hh1[col]); }
    }
    f32x2 h3 = mk2(0.f, 0.f);
    #pragma unroll 2
    for (int t = 0; t < TT; ++t) {
      spin_ge(vc + 2, 4 * (t + 1));               // h2[t] ready (early)
      __threadfence_block();
      const short* sx = S2 + (t & 3) * SLOT;
      const bfrag ax0 = *(const bfrag*)(sx + lc * SR + kb);
      const bfrag ax1 = *(const bfrag*)(sx + lc * SR + 32 + kb);
      facc rz[2], axn;
      #pragma unroll
      for (int G = 0; G < 2; ++G) {
        facc z = MFMA(ax0, gxf[G][0], brz4[G]);
        z = MFMA(ax1, gxf[G][1], z);
        rz[G] = z;
      }
      axn = MFMA(ax0, gxf[2][0], bnx4);
      axn = MFMA(ax1, gxf[2][1], axn);
      if (t >= 1) spin_ge(vc + 3, 4 * t);         // own group done t-1
      __threadfence_block();
      const short* sh = S3 + ((t - 1) & 3) * SLOT;
      const bfrag ah0 = *(const bfrag*)(sh + lc * SR + kb);
      const bfrag ah1 = *(const bfrag*)(sh + lc * SR + 32 + kb);
      facc ahn = MFMA(ah0, ghf[2][0], bnh4);
      ahn = MFMA(ah1, ghf[2][1], ahn);
      #pragma unroll
      for (int G = 0; G < 2; ++G) {
        rz[G] = MFMA(ah0, ghf[G][0], rz[G]);
        rz[G] = MFMA(ah1, ghf[G][1], rz[G]);
      }
      const f32x2 r_ = sigmP2(mk2(rz[0][0], rz[0][1]));
      const f32x2 z_ = sigmP2(mk2(rz[1][0], rz[1][1]));
      const f32x2 n_ = tanhP2(mk2(axn[0], axn[1]) + r_ * mk2(ahn[0], ahn[1]));
      h3 = n_ + z_ * (h3 - n_);
      const unsigned pk = pk_bf16(h3.x, h3.y);
      short* d = S3 + (t & 3) * SLOT;
      d[wrbase]      = (short)pk;
      d[wrbase + SR] = (short)(pk >> 16);
      __threadfence_block();
      if (l == 0) atomicAdd(&cnt[3], 1);
    }
    // final hidden state -> hfin (batch rows 2lq, 2lq+1)
    hfin[2 * lq][lo4 * 16 + lc]     = h3.x;
    hfin[2 * lq + 1][lo4 * 16 + lc] = h3.y;
  }

  __syncthreads();
  if (tid < 8) {
    float s = fc_b[0];
    #pragma unroll 8
    for (int d = 0; d < 64; ++d) s += hfin[tid][d] * fc_w[d];
    out[rb0 + tid] = s;
  }
}

extern "C" void kernel_launch(void* const* d_in, const int* in_sizes, int n_in,
                              void* d_out, int out_size, void* d_ws, size_t ws_size,
                              hipStream_t stream) {
  const float* x      = (const float*)d_in[0];
  const float* lw_ih0 = (const float*)d_in[1];
  const float* lw_hh0 = (const float*)d_in[2];
  const float* lb_ih0 = (const float*)d_in[3];
  const float* lb_hh0 = (const float*)d_in[4];
  const float* lw_ih1 = (const float*)d_in[5];
  const float* lw_hh1 = (const float*)d_in[6];
  const float* lb_ih1 = (const float*)d_in[7];
  const float* lb_hh1 = (const float*)d_in[8];
  const float* gw_ih0 = (const float*)d_in[9];
  const float* gw_hh0 = (const float*)d_in[10];
  const float* gb_ih0 = (const float*)d_in[11];
  const float* gb_hh0 = (const float*)d_in[12];
  const float* gw_ih1 = (const float*)d_in[13];
  const float* gw_hh1 = (const float*)d_in[14];
  const float* gb_ih1 = (const float*)d_in[15];
  const float* gb_hh1 = (const float*)d_in[16];
  const float* fc_w   = (const float*)d_in[17];
  const float* fc_b   = (const float*)d_in[18];

  rnn_fused<<<dim3(2048 / 8), dim3(1024), 0, stream>>>(
      x, lw_ih0, lw_hh0, lb_ih0, lb_hh0, lw_ih1, lw_hh1, lb_ih1, lb_hh1,
      gw_ih0, gw_hh0, gb_ih0, gb_hh0, gw_ih1, gw_hh1, gb_ih1, gb_hh1,
      fc_w, fc_b, (float*)d_out);
}